// Round 9
// baseline (899.338 us; speedup 1.0000x reference)
//
#include <hip/hip_runtime.h>
#include <hip/hip_bf16.h>

#define H 1024
#define T 2048
#define B 32
#define BM 128        // rows per block (t-tile)
#define NCOLT 8       // column tiles
#define BCOLS 128     // cols per block

typedef __attribute__((ext_vector_type(8))) __bf16 bf16x8;
typedef __attribute__((ext_vector_type(16))) float f32x16;
typedef __attribute__((ext_vector_type(8))) unsigned short u16x8;

__device__ __forceinline__ unsigned short f2bf(float f) {
    unsigned int x = __float_as_uint(f);
    x += 0x7fffu + ((x >> 16) & 1u);
    return (unsigned short)(x >> 16);
}

__device__ __forceinline__ float fast_tanh(float x) {
    float t = __expf(2.0f * x);
    return 1.0f - 2.0f * __builtin_amdgcn_rcpf(t + 1.0f);
}

// 8 floats -> bf16x8 via native casts (RTNE; compiler packs with v_cvt_pk_bf16_f32)
__device__ __forceinline__ bf16x8 cvt8(float4 x, float4 y) {
    bf16x8 r;
    r[0] = (__bf16)x.x; r[1] = (__bf16)x.y; r[2] = (__bf16)x.z; r[3] = (__bf16)x.w;
    r[4] = (__bf16)y.x; r[5] = (__bf16)y.y; r[6] = (__bf16)y.z; r[7] = (__bf16)y.w;
    return r;
}

// Pack W2 = W[:, H:2H] into bf16, layout Wp[kg][n][8] (kg = k>>3), 16B per (kg,n)
__global__ __launch_bounds__(256) void prep_w_kernel(const float* __restrict__ W,
                                                     unsigned short* __restrict__ Wp) {
    int gid = blockIdx.x * 256 + threadIdx.x;   // 131072 total
    int n = gid & (H - 1);
    int kg = gid >> 10;                          // 0..127
    const float* srcp = W + (size_t)n * (2 * H) + H + kg * 8;
    float4 f0 = *(const float4*)(srcp);
    float4 f1 = *(const float4*)(srcp + 4);
    u16x8 o;
    o[0] = f2bf(f0.x); o[1] = f2bf(f0.y); o[2] = f2bf(f0.z); o[3] = f2bf(f0.w);
    o[4] = f2bf(f1.x); o[5] = f2bf(f1.y); o[6] = f2bf(f1.z); o[7] = f2bf(f1.w);
    *(u16x8*)(Wp + (size_t)gid * 8) = o;
}

// hp[b][h] = sum_d hidden[b][d]*W[h][d] + bias[h], k-split x4 + shuffle reduce
__global__ __launch_bounds__(256) void prep_hp_kernel(const float* __restrict__ hidden,
                                                      const float* __restrict__ W,
                                                      const float* __restrict__ bias,
                                                      float* __restrict__ hp) {
    int b = blockIdx.y;
    int t = threadIdx.x;
    int h = blockIdx.x * 64 + (t >> 2);
    int kq = t & 3;
    const float* hid = hidden + (size_t)b * H + kq * 256;
    const float* wr = W + (size_t)h * (2 * H) + kq * 256;
    float acc = 0.f;
#pragma unroll 4
    for (int d = 0; d < 256; d += 4) {
        float4 wv = *(const float4*)(wr + d);
        float4 hv = *(const float4*)(hid + d);
        acc += wv.x * hv.x + wv.y * hv.y + wv.z * hv.z + wv.w * hv.w;
    }
    acc += __shfl_xor(acc, 1);
    acc += __shfl_xor(acc, 2);
    if (kq == 0) hp[(size_t)b * H + h] = acc + bias[h];
}

#define MFMA32(A, Bv, C) __builtin_amdgcn_mfma_f32_32x32x16_bf16(A, Bv, C, 0, 0, 0)

// Streaming fused energy kernel, zero K-loop barriers, zero K-loop branches.
// Block = (128-row tile, 128-col tile, b): 256 thr = 4 waves as 2(row)x2(col);
// wave = 64 rows x 64 cols, acc = 4 x f32x16 (64 AGPR). A streams fp32 directly
// from enc (cvt at use); B streams bf16 from Wp (L2). Depth-2 rolling prefetch,
// wrapped k-index (nit & 63) keeps every load unconditional -> counted vmcnt.
__global__ __launch_bounds__(256, 3) void energy_kernel(const float* __restrict__ enc,
                                                        const float* __restrict__ hp,
                                                        const float* __restrict__ vvec,
                                                        const unsigned short* __restrict__ Wp,
                                                        float* __restrict__ sc_part) {
    __shared__ float scpart[4][BM];   // 2 KB

    const int tid = threadIdx.x;
    const int b = blockIdx.z;
    const int t0 = blockIdx.x * BM;
    const int c0 = blockIdx.y * BCOLS;
    const int wave = tid >> 6;
    const int lane = tid & 63;
    const int l31 = lane & 31;
    const int hi = lane >> 5;
    const int wr = wave >> 1;     // row-half 0..1
    const int wc = wave & 1;      // col-group 0..1

    // A per-lane row pointers (fp32, k-offset = nit*16 + hi*8 handled per step)
    const float* ap0 = enc + ((size_t)b * T + t0 + wr * 64 + l31) * H + hi * 8;
    const float* ap1 = ap0 + (size_t)32 * H;
    // B per-lane pointer: col = c0 + wc*64 + {l31, +32}; page kg = it*2 + hi
    const unsigned short* wp_base = Wp + (size_t)(c0 + wc * 64 + l31) * 8 + (size_t)hi * (H * 8);

    f32x16 acc00, acc01, acc10, acc11;
#pragma unroll
    for (int i = 0; i < 16; ++i) { acc00[i] = 0.f; acc01[i] = 0.f; acc10[i] = 0.f; acc11[i] = 0.f; }

    // ---- prologue: depth-2 rolling preload (it=0 -> A-parity, it=1 -> B-parity) ----
    float4 fA00 = *(const float4*)(ap0);
    float4 fA01 = *(const float4*)(ap0 + 4);
    float4 fA10 = *(const float4*)(ap1);
    float4 fA11 = *(const float4*)(ap1 + 4);
    bf16x8 bA0 = *(const bf16x8*)(wp_base);
    bf16x8 bA1 = *(const bf16x8*)(wp_base + 256);
    float4 fB00 = *(const float4*)(ap0 + 16);
    float4 fB01 = *(const float4*)(ap0 + 20);
    float4 fB10 = *(const float4*)(ap1 + 16);
    float4 fB11 = *(const float4*)(ap1 + 20);
    bf16x8 bB0 = *(const bf16x8*)(wp_base + (size_t)H * 16);
    bf16x8 bB1 = *(const bf16x8*)(wp_base + (size_t)H * 16 + 256);

    // Rolling invariant: at STEP(KI) of chunk j, regs hold it = 4j+KI; reload (it+2)&63
    // into the same slot (wrap keeps loads unconditional; wrapped loads are never consumed).
#define STEP(KI, F00, F01, F10, F11, BC0, BC1)                                 \
    {                                                                          \
        bf16x8 a0 = cvt8(F00, F01);                                            \
        bf16x8 a1 = cvt8(F10, F11);                                            \
        __builtin_amdgcn_s_setprio(1);                                         \
        acc00 = MFMA32(a0, BC0, acc00);                                        \
        acc01 = MFMA32(a0, BC1, acc01);                                        \
        acc10 = MFMA32(a1, BC0, acc10);                                        \
        acc11 = MFMA32(a1, BC1, acc11);                                        \
        __builtin_amdgcn_s_setprio(0);                                         \
        const int nitw = (j * 4 + (KI) + 2) & 63;                              \
        const size_t ao = (size_t)nitw * 16;                                   \
        F00 = *(const float4*)(ap0 + ao);                                      \
        F01 = *(const float4*)(ap0 + ao + 4);                                  \
        F10 = *(const float4*)(ap1 + ao);                                      \
        F11 = *(const float4*)(ap1 + ao + 4);                                  \
        const unsigned short* bp = wp_base + (size_t)nitw * (H * 16);          \
        BC0 = *(const bf16x8*)(bp);                                            \
        BC1 = *(const bf16x8*)(bp + 256);                                      \
    }

    for (int j = 0; j < 16; ++j) {
        STEP(0, fA00, fA01, fA10, fA11, bA0, bA1)
        STEP(1, fB00, fB01, fB10, fB11, bB0, bB1)
        STEP(2, fA00, fA01, fA10, fA11, bA0, bA1)
        STEP(3, fB00, fB01, fB10, fB11, bB0, bB1)
    }
#undef STEP

    // ---- fused epilogue: tanh + v-dot over this wave's 64 cols ----
    const size_t bH = (size_t)b * H;
    const int col0 = c0 + wc * 64 + l31;
    const int col1 = col0 + 32;
    const float hp0 = hp[bH + col0], hp1 = hp[bH + col1];
    const float v0 = vvec[col0], v1 = vvec[col1];
    float psc[2][16];
#pragma unroll
    for (int r = 0; r < 16; ++r) {
        psc[0][r] = v0 * fast_tanh(acc00[r] + hp0) + v1 * fast_tanh(acc01[r] + hp1);
        psc[1][r] = v0 * fast_tanh(acc10[r] + hp0) + v1 * fast_tanh(acc11[r] + hp1);
    }

#pragma unroll
    for (int rg = 0; rg < 2; ++rg)
#pragma unroll
        for (int r = 0; r < 16; ++r) {
            float s = psc[rg][r];
            s += __shfl_xor(s, 1);
            s += __shfl_xor(s, 2);
            s += __shfl_xor(s, 4);
            s += __shfl_xor(s, 8);
            s += __shfl_xor(s, 16);
            psc[rg][r] = s;
        }
    if (l31 == 0) {
#pragma unroll
        for (int rg = 0; rg < 2; ++rg)
#pragma unroll
            for (int r = 0; r < 16; ++r) {
                int m = wr * 64 + rg * 32 + (r & 3) + 8 * (r >> 2) + 4 * hi;
                scpart[wave][m] = psc[rg][r];
            }
    }
    __syncthreads();
    if (tid < BM) {
        const int wbase = (tid >> 6) * 2;   // the 2 waves holding this row-half
        float s = scpart[wbase][tid] + scpart[wbase + 1][tid];
        sc_part[((size_t)blockIdx.y * B + b) * T + t0 + tid] = s;
    }
}

__global__ __launch_bounds__(256) void softmax_kernel(const float* __restrict__ sc,
                                                      float* __restrict__ out) {
    int b = blockIdx.x;
    int tid = threadIdx.x;
    int wave = tid >> 6, lane = tid & 63;
    float vals[8];
    float m = -1e30f;
#pragma unroll
    for (int i = 0; i < 8; ++i) {
        int idx = tid + 256 * i;
        float s = 0.f;
#pragma unroll
        for (int p = 0; p < NCOLT; ++p) s += sc[((size_t)p * B + b) * T + idx];
        vals[i] = s;
        m = fmaxf(m, s);
    }
#pragma unroll
    for (int s = 1; s < 64; s <<= 1) m = fmaxf(m, __shfl_xor(m, s));
    __shared__ float red[4];
    __shared__ float red2[4];
    if (lane == 0) red[wave] = m;
    __syncthreads();
    m = fmaxf(fmaxf(red[0], red[1]), fmaxf(red[2], red[3]));
    float sum = 0.f;
#pragma unroll
    for (int i = 0; i < 8; ++i) { vals[i] = expf(vals[i] - m); sum += vals[i]; }
#pragma unroll
    for (int s = 1; s < 64; s <<= 1) sum += __shfl_xor(sum, s);
    if (lane == 0) red2[wave] = sum;
    __syncthreads();
    sum = red2[0] + red2[1] + red2[2] + red2[3];
    float inv = 1.0f / sum;
#pragma unroll
    for (int i = 0; i < 8; ++i) out[(size_t)b * T + tid + 256 * i] = vals[i] * inv;
}

extern "C" void kernel_launch(void* const* d_in, const int* in_sizes, int n_in,
                              void* d_out, int out_size, void* d_ws, size_t ws_size,
                              hipStream_t stream) {
    (void)in_sizes; (void)n_in; (void)out_size; (void)ws_size;
    const float* hidden = (const float*)d_in[0];   // [1,B,H]
    const float* enc    = (const float*)d_in[1];   // [B,T,H]
    const float* W      = (const float*)d_in[2];   // [H,2H]
    const float* bias   = (const float*)d_in[3];   // [H]
    const float* v      = (const float*)d_in[4];   // [H]
    float* out = (float*)d_out;                    // [B,1,T]

    unsigned short* Wp = (unsigned short*)d_ws;                               // 2 MB
    float* hp = (float*)((char*)d_ws + 2 * 1024 * 1024);                      // 128 KB
    float* sc = (float*)((char*)d_ws + 2 * 1024 * 1024 + 128 * 1024);         // 2 MB (8 partials)

    prep_w_kernel<<<dim3(512), dim3(256), 0, stream>>>(W, Wp);
    prep_hp_kernel<<<dim3(16, B), dim3(256), 0, stream>>>(hidden, W, bias, hp);
    energy_kernel<<<dim3(T / BM, NCOLT, B), dim3(256), 0, stream>>>(enc, hp, v, Wp, sc);
    softmax_kernel<<<dim3(B), dim3(256), 0, stream>>>(sc, out);
}

// Round 10
// 225.481 us; speedup vs baseline: 3.9885x; 3.9885x over previous
//
#include <hip/hip_runtime.h>
#include <hip/hip_bf16.h>

#define H 1024
#define T 2048
#define B 32
#define BM 64         // rows per block (t-tile)
#define BKC 128       // k per LDS chunk
#define NCHUNK 8      // H / BKC

typedef __attribute__((ext_vector_type(8))) __bf16 bf16x8;
typedef __attribute__((ext_vector_type(16))) float f32x16;
typedef __attribute__((ext_vector_type(8))) unsigned short u16x8;

__device__ __forceinline__ unsigned short f2bf(float f) {
    unsigned int x = __float_as_uint(f);
    x += 0x7fffu + ((x >> 16) & 1u);
    return (unsigned short)(x >> 16);
}

__device__ __forceinline__ float fast_tanh(float x) {
    float t = __expf(2.0f * x);
    return 1.0f - 2.0f * __builtin_amdgcn_rcpf(t + 1.0f);
}

// Pack W2 = W[:, H:2H] into bf16, layout Wp[kg][n][8] (kg = k>>3), 16B per (kg,n)
__global__ __launch_bounds__(256) void prep_w_kernel(const float* __restrict__ W,
                                                     unsigned short* __restrict__ Wp) {
    int gid = blockIdx.x * 256 + threadIdx.x;   // 131072 total
    int n = gid & (H - 1);
    int kg = gid >> 10;                          // 0..127
    const float* srcp = W + (size_t)n * (2 * H) + H + kg * 8;
    float4 f0 = *(const float4*)(srcp);
    float4 f1 = *(const float4*)(srcp + 4);
    u16x8 o;
    o[0] = f2bf(f0.x); o[1] = f2bf(f0.y); o[2] = f2bf(f0.z); o[3] = f2bf(f0.w);
    o[4] = f2bf(f1.x); o[5] = f2bf(f1.y); o[6] = f2bf(f1.z); o[7] = f2bf(f1.w);
    *(u16x8*)(Wp + (size_t)gid * 8) = o;
}

// hp[b][h] = sum_d hidden[b][d]*W[h][d] + bias[h], k-split x4 + shuffle reduce
__global__ __launch_bounds__(256) void prep_hp_kernel(const float* __restrict__ hidden,
                                                      const float* __restrict__ W,
                                                      const float* __restrict__ bias,
                                                      float* __restrict__ hp) {
    int b = blockIdx.y;
    int t = threadIdx.x;
    int h = blockIdx.x * 64 + (t >> 2);
    int kq = t & 3;
    const float* hid = hidden + (size_t)b * H + kq * 256;
    const float* wr = W + (size_t)h * (2 * H) + kq * 256;
    float acc = 0.f;
#pragma unroll 4
    for (int d = 0; d < 256; d += 4) {
        float4 wv = *(const float4*)(wr + d);
        float4 hv = *(const float4*)(hid + d);
        acc += wv.x * hv.x + wv.y * hv.y + wv.z * hv.z + wv.w * hv.w;
    }
    acc += __shfl_xor(acc, 1);
    acc += __shfl_xor(acc, 2);
    if (kq == 0) hp[(size_t)b * H + h] = acc + bias[h];
}

#define MFMA32(A, Bv, C) __builtin_amdgcn_mfma_f32_32x32x16_bf16(A, Bv, C, 0, 0, 0)

// Single fused kernel, NCOLT=1: block = (64-row t-tile, b), 1024 thr = 16 waves;
// wave w owns cols [64w, 64w+64) x all 64 rows. acc = 4 x f32x16 = 64 AGPR.
// A: enc fp32 read ONCE from HBM, reg-staged (cvt once) into LDS bf16, double-buffered.
//   LDS layout: page ks (16 k-elems? no: 8 bf16 = 16B unit) -> addr = ks*1024 + ((row^(ks&7))<<4),
//   ks 0..15 per 128-k chunk, row 0..63. Reads: 32 consecutive swizzled rows -> conflict-free.
// B: Wp bf16 streamed from L2, branchless wrapped depth-2 rolling prefetch (R8-proven).
__global__ __launch_bounds__(1024, 4) void energy_kernel(const float* __restrict__ enc,
                                                         const float* __restrict__ hp,
                                                         const float* __restrict__ vvec,
                                                         const unsigned short* __restrict__ Wp,
                                                         float* __restrict__ scores) {
    __shared__ __align__(16) unsigned short Abuf[2][BM * BKC];  // 2 x 16 KB
    __shared__ float scpart[16][BM];                            // 4 KB

    const int tid = threadIdx.x;
    const int b = blockIdx.y;
    const int t0 = blockIdx.x * BM;
    const int wave = tid >> 6;
    const int lane = tid & 63;
    const int l31 = lane & 31;
    const int hi = lane >> 5;

    // staging: thread -> (row = tid>>4 in 0..63, kf = tid&15); reads 32B fp32, writes 16B bf16
    const int st_row = tid >> 4;
    const int st_kf = tid & 15;
    const float* st_src = enc + ((size_t)b * T + t0 + st_row) * H + st_kf * 8;
    char* Ab0 = (char*)&Abuf[0][0];
    char* st_dst = Ab0 + st_kf * 1024 + (((st_row ^ (st_kf & 7))) << 4);

    // B stream: global k-step nit (0..63): kg = nit*2 + hi; col = wave*64 + {l31, l31+32}
    const unsigned short* wp_base = Wp + (size_t)(wave * 64 + l31) * 8 + (size_t)hi * (H * 8);

    f32x16 acc00, acc01, acc10, acc11;
#pragma unroll
    for (int i = 0; i < 16; ++i) { acc00[i] = 0.f; acc01[i] = 0.f; acc10[i] = 0.f; acc11[i] = 0.f; }

    const int rv0 = l31;        // a0 rows 0..31
    const int rv1 = 32 + l31;   // a1 rows 32..63

    // ---- prologue: stage chunk 0; preload B nit=0 (A-parity), nit=1 (B-parity) ----
    {
        float4 f0 = *(const float4*)(st_src);
        float4 f1 = *(const float4*)(st_src + 4);
        u16x8 o;
        o[0] = f2bf(f0.x); o[1] = f2bf(f0.y); o[2] = f2bf(f0.z); o[3] = f2bf(f0.w);
        o[4] = f2bf(f1.x); o[5] = f2bf(f1.y); o[6] = f2bf(f1.z); o[7] = f2bf(f1.w);
        *(u16x8*)st_dst = o;
    }
    bf16x8 bA0 = *(const bf16x8*)(wp_base);
    bf16x8 bA1 = *(const bf16x8*)(wp_base + 256);
    bf16x8 bB0 = *(const bf16x8*)(wp_base + (size_t)H * 16);
    bf16x8 bB1 = *(const bf16x8*)(wp_base + (size_t)H * 16 + 256);
    __syncthreads();

    // Rolling invariant: at STEP(KI) of chunk j, regs hold nit = 8j+KI; reload (nit+2)&63
    // (wrap keeps loads unconditional; wrapped loads land after their consumers - harmless).
#define STEP(KI, C0, C1)                                                       \
    {                                                                          \
        const int ks = (KI) * 2 + hi;                                          \
        const char* ap = Ab + ks * 1024;                                       \
        bf16x8 a0 = *(const bf16x8*)(ap + ((rv0 ^ (ks & 7)) << 4));            \
        bf16x8 a1 = *(const bf16x8*)(ap + ((rv1 ^ (ks & 7)) << 4));            \
        __builtin_amdgcn_s_setprio(1);                                         \
        acc00 = MFMA32(a0, C0, acc00);                                         \
        acc01 = MFMA32(a0, C1, acc01);                                         \
        acc10 = MFMA32(a1, C0, acc10);                                         \
        acc11 = MFMA32(a1, C1, acc11);                                         \
        __builtin_amdgcn_s_setprio(0);                                         \
        const int nitw = (j * 8 + (KI) + 2) & 63;                              \
        const unsigned short* bp = wp_base + (size_t)nitw * (H * 16);          \
        C0 = *(const bf16x8*)(bp);                                             \
        C1 = *(const bf16x8*)(bp + 256);                                       \
    }

    for (int j = 0; j < NCHUNK; ++j) {
        // issue next chunk's A loads early (T14: load-early, write-late)
        float4 f0, f1;
        const bool pfA = (j < NCHUNK - 1);
        if (pfA) {
            const float* p = st_src + (j + 1) * BKC;
            f0 = *(const float4*)(p);
            f1 = *(const float4*)(p + 4);
        }
        const char* Ab = Ab0 + (j & 1) * 16384;
        STEP(0, bA0, bA1)
        STEP(1, bB0, bB1)
        STEP(2, bA0, bA1)
        STEP(3, bB0, bB1)
        STEP(4, bA0, bA1)
        STEP(5, bB0, bB1)
        STEP(6, bA0, bA1)
        STEP(7, bB0, bB1)
        if (pfA) {
            u16x8 o;
            o[0] = f2bf(f0.x); o[1] = f2bf(f0.y); o[2] = f2bf(f0.z); o[3] = f2bf(f0.w);
            o[4] = f2bf(f1.x); o[5] = f2bf(f1.y); o[6] = f2bf(f1.z); o[7] = f2bf(f1.w);
            *(u16x8*)(st_dst + ((j + 1) & 1) * 16384) = o;
        }
        __syncthreads();
    }
#undef STEP

    // ---- fused epilogue: tanh + v-dot over this wave's 64 cols ----
    const size_t bH = (size_t)b * H;
    const int col0 = wave * 64 + l31;
    const int col1 = col0 + 32;
    const float hp0 = hp[bH + col0], hp1 = hp[bH + col1];
    const float v0 = vvec[col0], v1 = vvec[col1];
    float psc[2][16];
#pragma unroll
    for (int r = 0; r < 16; ++r) {
        psc[0][r] = v0 * fast_tanh(acc00[r] + hp0) + v1 * fast_tanh(acc01[r] + hp1);
        psc[1][r] = v0 * fast_tanh(acc10[r] + hp0) + v1 * fast_tanh(acc11[r] + hp1);
    }

#pragma unroll
    for (int rg = 0; rg < 2; ++rg)
#pragma unroll
        for (int r = 0; r < 16; ++r) {
            float s = psc[rg][r];
            s += __shfl_xor(s, 1);
            s += __shfl_xor(s, 2);
            s += __shfl_xor(s, 4);
            s += __shfl_xor(s, 8);
            s += __shfl_xor(s, 16);
            psc[rg][r] = s;
        }
    if (l31 == 0) {
#pragma unroll
        for (int rg = 0; rg < 2; ++rg)
#pragma unroll
            for (int r = 0; r < 16; ++r) {
                int m = rg * 32 + (r & 3) + 8 * (r >> 2) + 4 * hi;
                scpart[wave][m] = psc[rg][r];
            }
    }
    __syncthreads();
    if (tid < BM) {
        float s = 0.f;
#pragma unroll
        for (int w = 0; w < 16; ++w) s += scpart[w][tid];
        scores[(size_t)b * T + t0 + tid] = s;
    }
}

__global__ __launch_bounds__(256) void softmax_kernel(const float* __restrict__ sc,
                                                      float* __restrict__ out) {
    int b = blockIdx.x;
    int tid = threadIdx.x;
    int wave = tid >> 6, lane = tid & 63;
    const float* row = sc + (size_t)b * T;
    float vals[8];
    float m = -1e30f;
#pragma unroll
    for (int i = 0; i < 8; ++i) { vals[i] = row[tid + 256 * i]; m = fmaxf(m, vals[i]); }
#pragma unroll
    for (int s = 1; s < 64; s <<= 1) m = fmaxf(m, __shfl_xor(m, s));
    __shared__ float red[4];
    __shared__ float red2[4];
    if (lane == 0) red[wave] = m;
    __syncthreads();
    m = fmaxf(fmaxf(red[0], red[1]), fmaxf(red[2], red[3]));
    float sum = 0.f;
#pragma unroll
    for (int i = 0; i < 8; ++i) { vals[i] = expf(vals[i] - m); sum += vals[i]; }
#pragma unroll
    for (int s = 1; s < 64; s <<= 1) sum += __shfl_xor(sum, s);
    if (lane == 0) red2[wave] = sum;
    __syncthreads();
    sum = red2[0] + red2[1] + red2[2] + red2[3];
    float inv = 1.0f / sum;
#pragma unroll
    for (int i = 0; i < 8; ++i) out[(size_t)b * T + tid + 256 * i] = vals[i] * inv;
}

extern "C" void kernel_launch(void* const* d_in, const int* in_sizes, int n_in,
                              void* d_out, int out_size, void* d_ws, size_t ws_size,
                              hipStream_t stream) {
    (void)in_sizes; (void)n_in; (void)out_size; (void)ws_size;
    const float* hidden = (const float*)d_in[0];   // [1,B,H]
    const float* enc    = (const float*)d_in[1];   // [B,T,H]
    const float* W      = (const float*)d_in[2];   // [H,2H]
    const float* bias   = (const float*)d_in[3];   // [H]
    const float* v      = (const float*)d_in[4];   // [H]
    float* out = (float*)d_out;                    // [B,1,T]

    unsigned short* Wp = (unsigned short*)d_ws;                               // 2 MB
    float* hp = (float*)((char*)d_ws + 2 * 1024 * 1024);                      // 128 KB
    float* sc = (float*)((char*)d_ws + 2 * 1024 * 1024 + 128 * 1024);         // 256 KB

    prep_w_kernel<<<dim3(512), dim3(256), 0, stream>>>(W, Wp);
    prep_hp_kernel<<<dim3(16, B), dim3(256), 0, stream>>>(hidden, W, bias, hp);
    energy_kernel<<<dim3(T / BM, B), dim3(1024), 0, stream>>>(enc, hp, v, Wp, sc);
    softmax_kernel<<<dim3(B), dim3(256), 0, stream>>>(sc, out);
}